// Round 8
// baseline (269.621 us; speedup 1.0000x reference)
//
#include <hip/hip_runtime.h>
#include <hip/hip_bf16.h>

// GCN layer: out[b,n,o] = dis[b,n] * sum_m adj[b,n,m] * dis[b,m] * (x[b,m,:]@W[o,:] + bias[o])
//
// R8: k_main = 128x128 tile, 512 threads (8 waves of 64x32), BK=64 DOUBLE-buffered,
// grid 256 (1 block/CU). R7 staged-then-immediately-drained (no overlap); R4 had
// overlap but 155cyc windows << 800cyc latency. R8: stage window g+1 right after
// barrier g, consume window g -> the vmcnt(0) at barrier g+1 drains loads that had
// a full window (~620cyc MFMA + ds_reads) to land. LDS = 64KB exactly (2 bufs x
// (A 16KB + B 16KB)). Per-CU window: MFMA 620cyc / staging 570cyc overlapped.

#define BATCH 8
#define NN    2048
#define DIN   256
#define DOUT  256
#define RTOT  (BATCH * NN)   // 16384
#define AP    (NN + 32)      // 2080  padded abf row stride (elems)
#define HP    (RTOT + 32)    // 16416 padded hT row stride (elems)

typedef short  bf16x8  __attribute__((ext_vector_type(8)));
typedef short  short4v __attribute__((ext_vector_type(4)));
typedef float  f32x4   __attribute__((ext_vector_type(4)));

__device__ __forceinline__ short f2bf(float f) {
    union { float f; unsigned u; } v; v.f = f;
    unsigned r = v.u + 0x7fffu + ((v.u >> 16) & 1u);   // RNE
    return (short)(r >> 16);
}

__device__ __forceinline__ void gl_lds16(const unsigned short* g, unsigned short* l) {
    __builtin_amdgcn_global_load_lds(
        (const __attribute__((address_space(1))) unsigned int*)g,
        (__attribute__((address_space(3))) unsigned int*)l, 16, 0, 0);
}

// ---------------- K1: degrees -> dis, and adj -> bf16 (padded rows) ----------------
__global__ __launch_bounds__(256) void k_degree_cvt(const float* __restrict__ adj,
                                                    float* __restrict__ dis,
                                                    unsigned short* __restrict__ abf) {
    const int row = blockIdx.x;                 // 0..16383
    const int n = row & (NN - 1);
    const int tid = threadIdx.x;
    const float4* rp4 = (const float4*)(adj + (size_t)row * NN);
    unsigned short* op = abf + (size_t)row * AP;

    float s = 0.f;
#pragma unroll
    for (int i = 0; i < 2; i++) {
        float4 v = rp4[tid + i * 256];
        s += (v.x + v.y) + (v.z + v.w);
        short4v sv = { f2bf(v.x), f2bf(v.y), f2bf(v.z), f2bf(v.w) };
        *(short4v*)(op + 4 * (tid + i * 256)) = sv;
    }
#pragma unroll
    for (int off = 32; off; off >>= 1) s += __shfl_down(s, off);
    __shared__ float red[4];
    if ((tid & 63) == 0) red[tid >> 6] = s;
    __syncthreads();
    if (tid == 0) {
        float tot  = (red[0] + red[1]) + (red[2] + red[3]);
        float diag = ((const float*)rp4)[n];
        dis[row]   = rsqrtf(tot - diag);
    }
}

// ---------------- K2: projection, transposed + dis-folded, padded hT ----------------
__global__ __launch_bounds__(256) void k_proj(const float* __restrict__ x,
                                              const float* __restrict__ W,
                                              const float* __restrict__ bias,
                                              const float* __restrict__ dis,
                                              unsigned short* __restrict__ hT) {
    const int mt  = blockIdx.y;           // 0..1   (o-tile of 128)
    const int nt  = blockIdx.x;           // 0..127 (r-tile of 128)
    const int tid = threadIdx.x;
    const int w = tid >> 6, lane = tid & 63;
    const int wr = w >> 1, wc = w & 1;
    const int l16 = lane & 15, quad = lane >> 4;

    __shared__ short As[128][32];
    __shared__ short Bs[128][32];

    f32x4 acc[4][4];
#pragma unroll
    for (int i = 0; i < 4; i++)
#pragma unroll
        for (int j = 0; j < 4; j++) acc[i][j] = (f32x4){0.f, 0.f, 0.f, 0.f};

    const float4* Wf4 = (const float4*)(W + (size_t)mt * 128 * DIN);
    const float4* Xf4 = (const float4*)(x + (size_t)nt * 128 * DIN);

    for (int kk = 0; kk < DIN / 32; kk++) {
        const int k0 = kk * 32;
        __syncthreads();
#pragma unroll
        for (int it = 0; it < 4; it++) {
            int idx = tid + it * 256;
            int r = idx >> 3, c = idx & 7;
            float4 va = Wf4[(size_t)r * (DIN / 4) + (k0 >> 2) + c];
            float4 vb = Xf4[(size_t)r * (DIN / 4) + (k0 >> 2) + c];
            short4v sa = { f2bf(va.x), f2bf(va.y), f2bf(va.z), f2bf(va.w) };
            short4v sb = { f2bf(vb.x), f2bf(vb.y), f2bf(vb.z), f2bf(vb.w) };
            *(short4v*)&As[r][c * 4] = sa;
            *(short4v*)&Bs[r][c * 4] = sb;
        }
        __syncthreads();
        bf16x8 af[4], bfv[4];
#pragma unroll
        for (int i = 0; i < 4; i++) af[i]  = *(bf16x8*)&As[wr * 64 + i * 16 + l16][quad * 8];
#pragma unroll
        for (int j = 0; j < 4; j++) bfv[j] = *(bf16x8*)&Bs[wc * 64 + j * 16 + l16][quad * 8];
#pragma unroll
        for (int i = 0; i < 4; i++)
#pragma unroll
            for (int j = 0; j < 4; j++)
                acc[i][j] = __builtin_amdgcn_mfma_f32_16x16x32_bf16(af[i], bfv[j], acc[i][j], 0, 0, 0);
    }

#pragma unroll
    for (int i = 0; i < 4; i++) {
        const int orow_base = mt * 128 + wr * 64 + i * 16 + quad * 4;
#pragma unroll
        for (int r = 0; r < 4; r++) {
            const int orow = orow_base + r;
            const float bb = bias[orow];
#pragma unroll
            for (int j = 0; j < 4; j++) {
                const int col = nt * 128 + wc * 64 + j * 16 + l16;
                float v = (acc[i][j][r] + bb) * dis[col];
                hT[(size_t)orow * HP + col] = (unsigned short)f2bf(v);
            }
        }
    }
}

// ---------------- K3: out = dis[n] * (abf @ hT), 128x128 tile, BK=64 dbuf ----------------
// Per batch: M=2048(n), K=2048(m), N=256(o). Grid 256 = 1 block/CU, 512 threads
// (8 waves: row-half rh = w>>2, col-quarter wc = w&3, each 64x32).
// bx&7=batch (XCD L2 affinity for hT), (bx>>3)&15=mtile, bx>>7=ctile.
__global__ __launch_bounds__(512, 2) void k_main(const unsigned short* __restrict__ abf,
                                                 const unsigned short* __restrict__ hT,
                                                 const float* __restrict__ dis,
                                                 float* __restrict__ out) {
    const int bx    = blockIdx.x;
    const int b     = bx & 7;
    const int mtile = (bx >> 3) & 15;
    const int ctile = bx >> 7;            // 0..1
    const int n0    = mtile * 128;
    const int o0    = ctile * 128;
    const int tid  = threadIdx.x;         // 0..511
    const int w    = tid >> 6, lane = tid & 63;
    const int l16  = lane & 15, quad = lane >> 4;
    const int rh   = w >> 2;              // 0..1  row half
    const int wc   = w & 3;               // 0..3  col quarter
    const int sr   = tid >> 2;            // 0..127 staging row
    const int sc   = (tid & 3) * 8;       // staging elem offset (x8 bf16 = 16B)

    // 64 KB total: 2 buffers x 2 sub-windows(32k) x 128 rows x 32 elems.
    __shared__ short As[2][2][128][32];   // adj rows(n)
    __shared__ short Bs[2][2][128][32];   // hT rows(o)

    const unsigned short* agp = abf + (size_t)(b * NN + n0 + sr) * AP + sc;
    const unsigned short* bgp = hT + (size_t)(o0 + sr) * HP + b * NN + sc;
    unsigned short* alp = (unsigned short*)&As[0][0][sr][sc];   // + (buf*2+s)*4096
    unsigned short* blp = (unsigned short*)&Bs[0][0][sr][sc];

    f32x4 acc[4][2];
#pragma unroll
    for (int i = 0; i < 4; i++)
#pragma unroll
        for (int j = 0; j < 2; j++) acc[i][j] = (f32x4){0.f, 0.f, 0.f, 0.f};

#define STAGE(buf, g) do {                                              \
        _Pragma("unroll")                                               \
        for (int _s = 0; _s < 2; _s++) {                                \
            const int _ko = (g) * 64 + _s * 32;                         \
            gl_lds16(agp + _ko, alp + ((buf) * 2 + _s) * 4096);         \
            gl_lds16(bgp + _ko, blp + ((buf) * 2 + _s) * 4096);         \
        }                                                               \
    } while (0)

    // Prologue: stage window 0 into buffer 0.
    STAGE(0, 0);

    for (int g = 0; g < NN / 64; g++) {   // 32 windows
        const int cur = g & 1, nxt = cur ^ 1;
        __syncthreads();                  // drains staging of window g (issued at g-1)
        if (g < NN / 64 - 1) STAGE(nxt, g + 1);
#pragma unroll
        for (int s = 0; s < 2; s++) {
            bf16x8 af[4], bfv[2];
#pragma unroll
            for (int i = 0; i < 4; i++)
                af[i]  = *(bf16x8*)&As[cur][s][rh * 64 + i * 16 + l16][quad * 8];
#pragma unroll
            for (int j = 0; j < 2; j++)
                bfv[j] = *(bf16x8*)&Bs[cur][s][wc * 32 + j * 16 + l16][quad * 8];
#pragma unroll
            for (int i = 0; i < 4; i++)
#pragma unroll
                for (int j = 0; j < 2; j++)
                    acc[i][j] = __builtin_amdgcn_mfma_f32_16x16x32_bf16(af[i], bfv[j], acc[i][j], 0, 0, 0);
        }
    }
#undef STAGE

    const float* disb = dis + (size_t)b * NN;
#pragma unroll
    for (int i = 0; i < 4; i++) {
#pragma unroll
        for (int r = 0; r < 4; r++) {
            const int nrow = n0 + rh * 64 + i * 16 + quad * 4 + r;
            const float dn = disb[nrow];
#pragma unroll
            for (int j = 0; j < 2; j++) {
                const int ocol = o0 + wc * 32 + j * 16 + l16;
                out[((size_t)b * NN + nrow) * DOUT + ocol] = dn * acc[i][j][r];
            }
        }
    }
}

extern "C" void kernel_launch(void* const* d_in, const int* in_sizes, int n_in,
                              void* d_out, int out_size, void* d_ws, size_t ws_size,
                              hipStream_t stream) {
    const float* x    = (const float*)d_in[0];
    const float* adj  = (const float*)d_in[1];
    const float* W    = (const float*)d_in[2];
    const float* bias = (const float*)d_in[3];
    float* out = (float*)d_out;

    float* dis = (float*)d_ws;                                             // 64 KB
    unsigned short* hT  = (unsigned short*)((char*)d_ws + 65536);          // 256*16416*2 = 8.4 MB
    unsigned short* abf = (unsigned short*)((char*)d_ws + 65536 + (size_t)DOUT * HP * 2); // 68 MB

    k_degree_cvt<<<RTOT, 256, 0, stream>>>(adj, dis, abf);
    k_proj<<<dim3(128, 2), 256, 0, stream>>>(x, W, bias, dis, hT);
    k_main<<<256, 512, 0, stream>>>(abf, hT, dis, out);
}